// Round 2
// baseline (1147.083 us; speedup 1.0000x reference)
//
#include <hip/hip_runtime.h>
#include <hip/hip_bf16.h>

// out[b, p] = req_to_token[req_pool_indices[b], p*PAGE_SIZE] >> 6
//             for p < ceil(page_kernel_lens[b] / PAGE_SIZE); else 0.
//
// Shapes (static): req_to_token [4096, 65536] i32, req_pool_indices [1024] i32,
// page_kernel_lens [1024] i32, out [1024, 1024] i32.
//
// Layout: one block (256 threads) per batch row; each thread handles 4
// consecutive pages -> int4 coalesced store, 4 independent gathers/thread
// (4-way MLP). Gathers are exec-predicated so masked-out lanes issue no
// memory traffic (tail pages beyond num_pages are never fetched).

#define PAGE_SHIFT  6
#define MAX_CTX     65536
#define MAX_PAGES   1024
#define BATCH       1024

__global__ __launch_bounds__(256)
void kv_page_index_kernel(const int* __restrict__ req_to_token,
                          const int* __restrict__ req_pool_indices,
                          const int* __restrict__ page_kernel_lens,
                          int* __restrict__ out) {
    const int b = blockIdx.x;                    // batch row (uniform per block)
    const int row = req_pool_indices[b];         // scalar load (block-uniform)
    const int len = page_kernel_lens[b];         // scalar load (block-uniform)
    const int num_pages = (len + 63) >> PAGE_SHIFT;

    const int p0 = threadIdx.x << 2;             // 4 pages per thread
    const int* __restrict__ rowp = req_to_token + (size_t)row * MAX_CTX;

    int4 v = make_int4(0, 0, 0, 0);
    // Addresses are always in-bounds (p0+3 <= 1023 < MAX_PAGES, row < POOL),
    // but predicate so masked lanes generate zero HBM traffic.
    if (p0 + 0 < num_pages) v.x = rowp[(size_t)(p0 + 0) << PAGE_SHIFT] >> PAGE_SHIFT;
    if (p0 + 1 < num_pages) v.y = rowp[(size_t)(p0 + 1) << PAGE_SHIFT] >> PAGE_SHIFT;
    if (p0 + 2 < num_pages) v.z = rowp[(size_t)(p0 + 2) << PAGE_SHIFT] >> PAGE_SHIFT;
    if (p0 + 3 < num_pages) v.w = rowp[(size_t)(p0 + 3) << PAGE_SHIFT] >> PAGE_SHIFT;

    // 16B-aligned coalesced store; also zeros the masked tail (d_out is poisoned).
    *reinterpret_cast<int4*>(out + ((size_t)b << 10) + p0) = v;
}

extern "C" void kernel_launch(void* const* d_in, const int* in_sizes, int n_in,
                              void* d_out, int out_size, void* d_ws, size_t ws_size,
                              hipStream_t stream) {
    const int* req_to_token     = (const int*)d_in[0];
    const int* req_pool_indices = (const int*)d_in[1];
    const int* page_kernel_lens = (const int*)d_in[2];
    int* out = (int*)d_out;

    kv_page_index_kernel<<<dim3(BATCH), dim3(256), 0, stream>>>(
        req_to_token, req_pool_indices, page_kernel_lens, out);
}